// Round 2
// baseline (255.026 us; speedup 1.0000x reference)
//
#include <hip/hip_runtime.h>

typedef __bf16 bf16;
typedef unsigned short u16;
typedef __attribute__((ext_vector_type(8))) __bf16 bf16x8;
typedef __attribute__((ext_vector_type(16))) float f32x16;
typedef __attribute__((ext_vector_type(2))) unsigned int uint2v;
typedef __attribute__((ext_vector_type(4))) unsigned int uint4v;

#define MFMA32(a, b, c) __builtin_amdgcn_mfma_f32_32x32x16_bf16(a, b, c, 0, 0, 0)

__device__ __forceinline__ u16 bbits(float f) {
  bf16 h = (bf16)f;
  return __builtin_bit_cast(u16, h);
}
__device__ __forceinline__ float bf2f(u16 u) {
  return (float)__builtin_bit_cast(bf16, u);
}
__device__ __forceinline__ bf16x8 ldg16(const u16* p) {
  return *reinterpret_cast<const bf16x8*>(p);  // 16B-aligned by construction
}
// 8-byte-aligned LDS read of 8 bf16 as two b64s (strides are 8B-aligned, not 16B)
__device__ __forceinline__ bf16x8 ld_p8(const u16* p) {
  uint2v a = *reinterpret_cast<const uint2v*>(p);
  uint2v b = *reinterpret_cast<const uint2v*>(p + 4);
  uint4v u;
  u.x = a.x; u.y = a.y; u.z = b.x; u.w = b.y;
  return __builtin_bit_cast(bf16x8, u);
}

// ---------------------------------------------------------------------------
// Projections: theta(HL) -> keys Kh/Kl [b][n][64] bf16 hi/lo
//              phi(HL)   -> queries Qh/Ql [b][n][64]
//              g(L)      -> values V [b][c][n] bf16
// fp32 VALU matvec, k-CHUNKED so registers never spill:
//   acc[32] (one thread owns 32 output channels) + x[32] (one 32-channel
//   k-chunk at a time) ~= 80 VGPR. Weight rows are wave-uniform -> s_load.
// Groups (blockIdx.y): 0,1 theta | 2,3 phi | 4,5 g.
// ---------------------------------------------------------------------------
__global__ __launch_bounds__(256) void pa_proj(
    const float* __restrict__ H, const float* __restrict__ L,
    const float* __restrict__ tw, const float* __restrict__ tb,
    const float* __restrict__ pw, const float* __restrict__ pb,
    const float* __restrict__ gw, const float* __restrict__ gb,
    u16* __restrict__ Qh, u16* __restrict__ Ql,
    u16* __restrict__ Kh, u16* __restrict__ Kl,
    u16* __restrict__ V) {
  int p = blockIdx.x * 256 + threadIdx.x;  // 0..16383 global position
  int b = p >> 12, n = p & 4095;           // b uniform per block
  int g = blockIdx.y;
  int c0 = (g & 1) * 32;
  float acc[32];
  if (g < 4) {
    const float* __restrict__ W = (g < 2) ? tw : pw;
    const float* __restrict__ bias = (g < 2) ? tb : pb;
#pragma unroll
    for (int o = 0; o < 32; ++o) acc[o] = bias[c0 + o];
#pragma unroll 1
    for (int kc = 0; kc < 4; ++kc) {
      const float* __restrict__ src = (kc < 2) ? H : L;
      int kb = (kc & 1) * 32;  // channel base within src
      float x[32];
#pragma unroll
      for (int k = 0; k < 32; ++k) x[k] = src[(b * 64 + kb + k) * 4096 + n];
#pragma unroll 4
      for (int o = 0; o < 32; ++o) {
        const float* wr = W + (c0 + o) * 128 + kc * 32;  // uniform -> s_load
#pragma unroll
        for (int k = 0; k < 32; ++k) acc[o] = fmaf(wr[k], x[k], acc[o]);
      }
    }
    u16* hi = (g < 2) ? Kh : Qh;
    u16* lo = (g < 2) ? Kl : Ql;
    int base = p * 64 + c0;
#pragma unroll
    for (int cc = 0; cc < 32; cc += 2) {
      float a0 = acc[cc], a1 = acc[cc + 1];
      u16 h0 = bbits(a0), h1 = bbits(a1);
      u16 l0 = bbits(a0 - bf2f(h0)), l1 = bbits(a1 - bf2f(h1));
      *reinterpret_cast<unsigned*>(hi + base + cc) = (unsigned)h0 | ((unsigned)h1 << 16);
      *reinterpret_cast<unsigned*>(lo + base + cc) = (unsigned)l0 | ((unsigned)l1 << 16);
    }
  } else {
#pragma unroll
    for (int o = 0; o < 32; ++o) acc[o] = gb[c0 + o];
#pragma unroll 1
    for (int kc = 0; kc < 2; ++kc) {
      float x[32];
#pragma unroll
      for (int k = 0; k < 32; ++k) x[k] = L[(b * 64 + kc * 32 + k) * 4096 + n];
#pragma unroll 4
      for (int o = 0; o < 32; ++o) {
        const float* wr = gw + (c0 + o) * 64 + kc * 32;  // uniform -> s_load
#pragma unroll
        for (int k = 0; k < 32; ++k) acc[o] = fmaf(wr[k], x[k], acc[o]);
      }
    }
#pragma unroll
    for (int o = 0; o < 32; ++o) V[(b * 64 + c0 + o) * 4096 + n] = bbits(acc[o]);
  }
}

// ---------------------------------------------------------------------------
// Prep: conv weights -> Wt[dy*3+dx][c_out][c_in] bf16; BN folded: out = A*conv+B
// ---------------------------------------------------------------------------
__global__ __launch_bounds__(256) void pa_prep(
    const float* __restrict__ cw, const float* __restrict__ cbias,
    const float* __restrict__ gamma, const float* __restrict__ beta,
    const float* __restrict__ mean, const float* __restrict__ var,
    u16* __restrict__ Wt, float* __restrict__ bnA, float* __restrict__ bnB) {
  int i = blockIdx.x * 256 + threadIdx.x;
  if (i < 36864) {
    int ci = i & 63, co = (i >> 6) & 63, s = i >> 12;  // s = dy*3+dx
    Wt[(s * 64 + co) * 64 + ci] = bbits(cw[(co * 64 + ci) * 9 + s]);
  }
  if (i < 64) {
    float rs = rsqrtf(var[i] + 1e-5f);
    float A = gamma[i] * rs;
    bnA[i] = A;
    bnB[i] = (cbias[i] - mean[i]) * A + beta[i];
  }
}

// ---------------------------------------------------------------------------
// Flash attention: O^T[c,m] = sum_n softmax_n(K[n,:]·Q[m,:]) * V[c,n]
// Block = (b, row y): m-tile 64. 4 waves split n 4-way (stride-interleaved
// 32-key tiles), private online-softmax state, merged via LDS at the end.
// mfma 32x32x16 bf16. QK in hi/lo split (3 mfma) for fp32-grade logits.
// A-frag: row=lane&31, k=(lane>>5)*8+j. B-frag: col=lane&31, k=(lane>>5)*8+j.
// C/D: col=lane&31, row=(r&3)+8*(r>>2)+4*(lane>>5).
// No __syncthreads in the K-loop (K/Q/V frags direct from global/L2; the
// only LDS use is the wave-private P C-layout->B-layout round trip).
// ---------------------------------------------------------------------------
__global__ __launch_bounds__(256, 1) void pa_flash(
    const u16* __restrict__ Qh, const u16* __restrict__ Ql,
    const u16* __restrict__ Kh, const u16* __restrict__ Kl,
    const u16* __restrict__ V, u16* __restrict__ E) {
  __shared__ u16 Pbuf[4][64 * 36];  // per-wave P, row stride 36 (2-way banks, 8B aligned)
  __shared__ float Obuf[64 * 67];   // merge buffer [c][m], stride 67
  __shared__ float MLm[4][2][32];
  __shared__ float MLl[4][2][32];
  __shared__ float Lstar[64];

  int tid = threadIdx.x;
  int w = tid >> 6, lane = tid & 63;
  int l31 = lane & 31, q2 = lane >> 5;
  int blk = blockIdx.x;
  int b = blk >> 6, y = blk & 63;
  int m0 = y * 64;
  int bq = b * 4096;

  // Q fragments (held in registers for the whole kernel): B-operand layout
  bf16x8 qh[2][4], ql[2][4];
#pragma unroll
  for (int mb = 0; mb < 2; ++mb)
#pragma unroll
    for (int kc = 0; kc < 4; ++kc) {
      int idx = (bq + m0 + mb * 32 + l31) * 64 + kc * 16 + q2 * 8;
      qh[mb][kc] = ldg16(Qh + idx);
      ql[mb][kc] = ldg16(Ql + idx);
    }

  f32x16 accO[2][2] = {};          // [cb][mb], C layout: row=c, col=m
  float Mm[2] = {-1e30f, -1e30f};  // running max per m-column (mb 0/1)
  float Ll[2] = {0.f, 0.f};        // running sum
  u16* mypb = &Pbuf[w][0];

#pragma unroll 1
  for (int it = 0; it < 32; ++it) {
    int n0 = it * 128 + w * 32;  // this wave's 32-key tile

    bf16x8 kh[4], kl[4];
#pragma unroll
    for (int kc = 0; kc < 4; ++kc) {
      int idx = (bq + n0 + l31) * 64 + kc * 16 + q2 * 8;
      kh[kc] = ldg16(Kh + idx);
      kl[kc] = ldg16(Kl + idx);
    }
    bf16x8 vf[2][2];
#pragma unroll
    for (int cbi = 0; cbi < 2; ++cbi)
#pragma unroll
      for (int kch = 0; kch < 2; ++kch)
        vf[cbi][kch] = ldg16(V + (b * 64 + cbi * 32 + l31) * 4096 + n0 + kch * 16 + q2 * 8);

    // S^T = K · Q^T with hi/lo split (drop kl*ql); two partial accs -> depth-6 chains
    f32x16 sA[2], sB[2];
#pragma unroll
    for (int mb = 0; mb < 2; ++mb) {
      f32x16 a = {};
      f32x16 b2 = {};
#pragma unroll
      for (int kc = 0; kc < 2; ++kc) {
        a = MFMA32(kh[kc], qh[mb][kc], a);
        a = MFMA32(kh[kc], ql[mb][kc], a);
        a = MFMA32(kl[kc], qh[mb][kc], a);
      }
#pragma unroll
      for (int kc = 2; kc < 4; ++kc) {
        b2 = MFMA32(kh[kc], qh[mb][kc], b2);
        b2 = MFMA32(kh[kc], ql[mb][kc], b2);
        b2 = MFMA32(kl[kc], qh[mb][kc], b2);
      }
      sA[mb] = a;
      sB[mb] = b2;
    }

    // online softmax (per m-column; lane holds 16 of the 32 n's, partner via xor-32)
#pragma unroll
    for (int mb = 0; mb < 2; ++mb) {
      float s[16];
#pragma unroll
      for (int r = 0; r < 16; ++r) s[r] = sA[mb][r] + sB[mb][r];
      float tmax = s[0];
#pragma unroll
      for (int r = 1; r < 16; ++r) tmax = fmaxf(tmax, s[r]);
      tmax = fmaxf(tmax, __shfl_xor(tmax, 32, 64));
      float newM = fmaxf(Mm[mb], tmax);
      float alpha = __expf(Mm[mb] - newM);
      Mm[mb] = newM;
      float pv[16];
      float psum = 0.f;
#pragma unroll
      for (int r = 0; r < 16; ++r) {
        pv[r] = __expf(s[r] - newM);
        psum += pv[r];
      }
      psum += __shfl_xor(psum, 32, 64);
      Ll[mb] = Ll[mb] * alpha + psum;
#pragma unroll
      for (int r = 0; r < 16; ++r) {
        accO[0][mb][r] *= alpha;
        accO[1][mb][r] *= alpha;
      }
      // P: C-layout regs -> LDS [m][n] (B-operand layout for PV). 4 consec n per reg-quad.
      u16* prow = mypb + (mb * 32 + l31) * 36;
#pragma unroll
      for (int rq = 0; rq < 4; ++rq) {
        unsigned lo = (unsigned)bbits(pv[rq * 4 + 0]) | ((unsigned)bbits(pv[rq * 4 + 1]) << 16);
        unsigned hi = (unsigned)bbits(pv[rq * 4 + 2]) | ((unsigned)bbits(pv[rq * 4 + 3]) << 16);
        uint2v uu;
        uu.x = lo;
        uu.y = hi;
        *reinterpret_cast<uint2v*>(prow + rq * 8 + q2 * 4) = uu;  // n = 8*rq + 4*q2 + 0..3
      }
    }

    // PV: O^T += V^T(A) · P^T(B)
#pragma unroll
    for (int mb = 0; mb < 2; ++mb) {
      const u16* prow = mypb + (mb * 32 + l31) * 36;
      bf16x8 p0 = ld_p8(prow + q2 * 8);       // k = n 0..15
      bf16x8 p1 = ld_p8(prow + 16 + q2 * 8);  // k = n 16..31
      accO[0][mb] = MFMA32(vf[0][0], p0, accO[0][mb]);
      accO[0][mb] = MFMA32(vf[0][1], p1, accO[0][mb]);
      accO[1][mb] = MFMA32(vf[1][0], p0, accO[1][mb]);
      accO[1][mb] = MFMA32(vf[1][1], p1, accO[1][mb]);
    }
  }

  // ---- merge the 4 waves' partial (O, M, l) ----
  if (q2 == 0) {
#pragma unroll
    for (int mb = 0; mb < 2; ++mb) {
      MLm[w][mb][l31] = Mm[mb];
      MLl[w][mb][l31] = Ll[mb];
    }
  }
  __syncthreads();
  float mysc[2];
#pragma unroll
  for (int mb = 0; mb < 2; ++mb) {
    float M = MLm[0][mb][l31];
    for (int ww = 1; ww < 4; ++ww) M = fmaxf(M, MLm[ww][mb][l31]);
    float ls = 0.f;
    for (int ww = 0; ww < 4; ++ww) ls += MLl[ww][mb][l31] * __expf(MLm[ww][mb][l31] - M);
    mysc[mb] = __expf(Mm[mb] - M);
    if (w == 0 && q2 == 0) Lstar[mb * 32 + l31] = ls;
  }
  for (int ww = 0; ww < 4; ++ww) {
    if (w == ww) {
#pragma unroll
      for (int cbi = 0; cbi < 2; ++cbi)
#pragma unroll
        for (int mb = 0; mb < 2; ++mb) {
          float sc = mysc[mb];
#pragma unroll
          for (int r = 0; r < 16; ++r) {
            int c = cbi * 32 + (r & 3) + 8 * (r >> 2) + 4 * q2;
            int m = mb * 32 + l31;
            float* dst = &Obuf[c * 67 + m];
            float v = accO[cbi][mb][r] * sc;
            if (ww == 0)
              *dst = v;
            else
              *dst += v;
          }
        }
    }
    __syncthreads();
  }
  // write E[b][m][c] bf16 (spatial-major for the conv's B-operand)
  int em = tid >> 2, ec0 = (tid & 3) * 16;
  float invl = 1.0f / Lstar[em];
  float vals[16];
#pragma unroll
  for (int j = 0; j < 16; ++j) vals[j] = Obuf[(ec0 + j) * 67 + em] * invl;
  uint4v u0, u1;
  u0.x = (unsigned)bbits(vals[0]) | ((unsigned)bbits(vals[1]) << 16);
  u0.y = (unsigned)bbits(vals[2]) | ((unsigned)bbits(vals[3]) << 16);
  u0.z = (unsigned)bbits(vals[4]) | ((unsigned)bbits(vals[5]) << 16);
  u0.w = (unsigned)bbits(vals[6]) | ((unsigned)bbits(vals[7]) << 16);
  u1.x = (unsigned)bbits(vals[8]) | ((unsigned)bbits(vals[9]) << 16);
  u1.y = (unsigned)bbits(vals[10]) | ((unsigned)bbits(vals[11]) << 16);
  u1.z = (unsigned)bbits(vals[12]) | ((unsigned)bbits(vals[13]) << 16);
  u1.w = (unsigned)bbits(vals[14]) | ((unsigned)bbits(vals[15]) << 16);
  u16* ep = E + (bq + m0 + em) * 64 + ec0;
  *reinterpret_cast<uint4v*>(ep) = u0;
  *reinterpret_cast<uint4v*>(ep + 8) = u1;
}

// ---------------------------------------------------------------------------
// Conv3x3(SAME)+BN+ReLU+residual as 9 shifted MFMA GEMMs.
// Block = (b, row y). LDS holds rows y-1..y+1 with x-halo, [x+1][c] stride 68.
// ---------------------------------------------------------------------------
__global__ __launch_bounds__(256) void pa_conv(
    const u16* __restrict__ E, const u16* __restrict__ Wt,
    const float* __restrict__ bnA, const float* __restrict__ bnB,
    const float* __restrict__ H, float* __restrict__ out) {
  __shared__ u16 Er[3][66 * 68];
  int tid = threadIdx.x;
  int blk = blockIdx.x;
  int b = blk >> 6, y = blk & 63;
  int lane = tid & 63;
  int l31 = lane & 31, q2 = lane >> 5;
  int wv = tid >> 6;
  int cbi = wv >> 1, mb = wv & 1;
  int s0 = (y == 0) ? 1 : 0;
  int s1 = (y == 63) ? 1 : 2;

  for (int s = s0; s <= s1; ++s) {
    int yy = y + s - 1;
#pragma unroll
    for (int rep = 0; rep < 2; ++rep) {
      int id = rep * 256 + tid;
      int x = id >> 3, co = (id & 7) * 8;
      const uint2v* src = reinterpret_cast<const uint2v*>(E + ((b * 4096 + yy * 64 + x) * 64 + co));
      uint2v a = src[0], b4 = src[1];
      u16* d = &Er[s][(x + 1) * 68 + co];
      *reinterpret_cast<uint2v*>(d) = a;
      *reinterpret_cast<uint2v*>(d + 4) = b4;
    }
  }
  if (tid < 96) {  // zero x-halo columns
    int s = tid >> 5, side = (tid >> 4) & 1, co = (tid & 15) * 4;
    uint2v z;
    z.x = 0;
    z.y = 0;
    *reinterpret_cast<uint2v*>(&Er[s][(side ? 65 : 0) * 68 + co]) = z;
  }
  __syncthreads();

  f32x16 acc = {};
  for (int s = s0; s <= s1; ++s) {
#pragma unroll
    for (int dx = 0; dx < 3; ++dx)
#pragma unroll
      for (int kc = 0; kc < 4; ++kc) {
        bf16x8 a = ldg16(Wt + ((s * 3 + dx) * 64 + cbi * 32 + l31) * 64 + kc * 16 + q2 * 8);
        const u16* pbr = &Er[s][(mb * 32 + l31 + dx) * 68 + kc * 16 + q2 * 8];
        bf16x8 bb = ld_p8(pbr);
        acc = MFMA32(a, bb, acc);
      }
  }
#pragma unroll
  for (int r = 0; r < 16; ++r) {
    int c = cbi * 32 + (r & 3) + 8 * (r >> 2) + 4 * q2;
    int x = mb * 32 + l31;
    float v = acc[r] * bnA[c] + bnB[c];
    v = fmaxf(v, 0.f);
    int idx = ((b * 64 + c) * 64 + y) * 64 + x;
    out[idx] = H[idx] + v;
  }
}

// ---------------------------------------------------------------------------
extern "C" void kernel_launch(void* const* d_in, const int* in_sizes, int n_in,
                              void* d_out, int out_size, void* d_ws, size_t ws_size,
                              hipStream_t stream) {
  (void)in_sizes; (void)n_in; (void)out_size; (void)ws_size;
  const float* H = (const float*)d_in[0];
  const float* L = (const float*)d_in[1];
  const float* tw = (const float*)d_in[2];
  const float* tb = (const float*)d_in[3];
  const float* pw = (const float*)d_in[4];
  const float* pb = (const float*)d_in[5];
  const float* gw = (const float*)d_in[6];
  const float* gb = (const float*)d_in[7];
  const float* cw = (const float*)d_in[8];
  const float* cb = (const float*)d_in[9];
  const float* gamma = (const float*)d_in[10];
  const float* beta = (const float*)d_in[11];
  const float* mean = (const float*)d_in[12];
  const float* var = (const float*)d_in[13];

  const int NC = 16384 * 64;  // 1M elements per [b][n][c] plane
  u16* Qh = (u16*)d_ws;
  u16* Ql = Qh + NC;
  u16* Kh = Ql + NC;
  u16* Kl = Kh + NC;
  u16* Vv = Kl + NC;
  u16* Eb = Vv + NC;
  u16* Wt = Eb + NC;
  float* bnA = (float*)(Wt + 36864);
  float* bnB = bnA + 64;

  pa_proj<<<dim3(64, 6), 256, 0, stream>>>(H, L, tw, tb, pw, pb, gw, gb, Qh, Ql, Kh, Kl, Vv);
  pa_prep<<<144, 256, 0, stream>>>(cw, cb, gamma, beta, mean, var, Wt, bnA, bnB);
  pa_flash<<<256, 256, 0, stream>>>(Qh, Ql, Kh, Kl, Vv, Eb);
  pa_conv<<<256, 256, 0, stream>>>(Eb, Wt, bnA, bnB, H, (float*)d_out);
}

// Round 3
// 179.224 us; speedup vs baseline: 1.4229x; 1.4229x over previous
//
#include <hip/hip_runtime.h>

typedef __bf16 bf16;
typedef unsigned short u16;
typedef __attribute__((ext_vector_type(8))) __bf16 bf16x8;
typedef __attribute__((ext_vector_type(16))) float f32x16;
typedef __attribute__((ext_vector_type(2))) unsigned int uint2v;
typedef __attribute__((ext_vector_type(4))) unsigned int uint4v;

#define MFMA32(a, b, c) __builtin_amdgcn_mfma_f32_32x32x16_bf16(a, b, c, 0, 0, 0)

__device__ __forceinline__ u16 bbits(float f) {
  bf16 h = (bf16)f;
  return __builtin_bit_cast(u16, h);
}
__device__ __forceinline__ float bf2f(u16 u) {
  return (float)__builtin_bit_cast(bf16, u);
}
__device__ __forceinline__ bf16x8 ldg16(const u16* p) {
  return *reinterpret_cast<const bf16x8*>(p);  // 16B-aligned by construction
}
// 8-byte-aligned LDS read of 8 bf16 as two b64s (strides are 8B-aligned, not 16B)
__device__ __forceinline__ bf16x8 ld_p8(const u16* p) {
  uint2v a = *reinterpret_cast<const uint2v*>(p);
  uint2v b = *reinterpret_cast<const uint2v*>(p + 4);
  uint4v u;
  u.x = a.x; u.y = a.y; u.z = b.x; u.w = b.y;
  return __builtin_bit_cast(bf16x8, u);
}
// split 8 fp32 into hi/lo bf16x8 fragments
__device__ __forceinline__ void split8(const float* xv, bf16x8& hi, bf16x8& lo) {
  uint4v hv, lv;
#pragma unroll
  for (int jp = 0; jp < 4; ++jp) {
    float a0 = xv[2 * jp], a1 = xv[2 * jp + 1];
    u16 h0 = bbits(a0), h1 = bbits(a1);
    u16 l0 = bbits(a0 - bf2f(h0)), l1 = bbits(a1 - bf2f(h1));
    unsigned hh = (unsigned)h0 | ((unsigned)h1 << 16);
    unsigned ll = (unsigned)l0 | ((unsigned)l1 << 16);
    if (jp == 0) { hv.x = hh; lv.x = ll; }
    else if (jp == 1) { hv.y = hh; lv.y = ll; }
    else if (jp == 2) { hv.z = hh; lv.z = ll; }
    else { hv.w = hh; lv.w = ll; }
  }
  hi = __builtin_bit_cast(bf16x8, hv);
  lo = __builtin_bit_cast(bf16x8, lv);
}

// ---------------------------------------------------------------------------
// Prep: conv weights -> Wt[dy*3+dx][c_out][c_in] bf16; BN folded: out = A*conv+B
// Also: theta/phi/g 1x1 weights -> hi/lo bf16 [out][in] for MFMA A-fragments.
// ---------------------------------------------------------------------------
__global__ __launch_bounds__(256) void pa_prep(
    const float* __restrict__ cw, const float* __restrict__ cbias,
    const float* __restrict__ gamma, const float* __restrict__ beta,
    const float* __restrict__ mean, const float* __restrict__ var,
    const float* __restrict__ tw, const float* __restrict__ pw, const float* __restrict__ gw,
    u16* __restrict__ Wt, float* __restrict__ bnA, float* __restrict__ bnB,
    u16* __restrict__ Wth, u16* __restrict__ Wtl,
    u16* __restrict__ Wph, u16* __restrict__ Wpl,
    u16* __restrict__ Wgh, u16* __restrict__ Wgl) {
  int i = blockIdx.x * 256 + threadIdx.x;
  if (i < 36864) {
    int ci = i & 63, co = (i >> 6) & 63, s = i >> 12;  // s = dy*3+dx
    Wt[(s * 64 + co) * 64 + ci] = bbits(cw[(co * 64 + ci) * 9 + s]);
  }
  if (i < 8192) {
    float v = tw[i];
    u16 h = bbits(v);
    Wth[i] = h;
    Wtl[i] = bbits(v - bf2f(h));
  } else if (i < 16384) {
    int j = i - 8192;
    float v = pw[j];
    u16 h = bbits(v);
    Wph[j] = h;
    Wpl[j] = bbits(v - bf2f(h));
  } else if (i < 20480) {
    int j = i - 16384;
    float v = gw[j];
    u16 h = bbits(v);
    Wgh[j] = h;
    Wgl[j] = bbits(v - bf2f(h));
  }
  if (i < 64) {
    float rs = rsqrtf(var[i] + 1e-5f);
    float A = gamma[i] * rs;
    bnA[i] = A;
    bnB[i] = (cbias[i] - mean[i]) * A + beta[i];
  }
}

// ---------------------------------------------------------------------------
// Projections as MFMA GEMM: theta(HL)->Kh/Kl [b][n][64], phi(HL)->Qh/Ql,
// g(L)->V [b][c][n]. Hi/lo bf16 split on both W and X (3 MFMA per product:
// hh + h*l + l*h) => fp32-grade precision. One wave owns 32 positions; X
// B-fragments built once in registers (64 coalesced fp32 loads + split),
// reused by theta/phi/g. No LDS, no barriers. Grid 256 x 128thr = 512 waves.
// ---------------------------------------------------------------------------
__device__ __forceinline__ void store_qk(const f32x16& a0, const f32x16& a1,
                                         const float* __restrict__ bias,
                                         u16* __restrict__ Hi, u16* __restrict__ Lo,
                                         int p, int q2) {
#pragma unroll
  for (int mt = 0; mt < 2; ++mt) {
    const f32x16& A = mt ? a1 : a0;
#pragma unroll
    for (int rq = 0; rq < 4; ++rq) {
      int chb = mt * 32 + rq * 8 + q2 * 4;
      float4 bb = *reinterpret_cast<const float4*>(bias + chb);
      float v0 = A[rq * 4 + 0] + bb.x;
      float v1 = A[rq * 4 + 1] + bb.y;
      float v2 = A[rq * 4 + 2] + bb.z;
      float v3 = A[rq * 4 + 3] + bb.w;
      u16 h0 = bbits(v0), h1 = bbits(v1), h2 = bbits(v2), h3 = bbits(v3);
      u16 l0 = bbits(v0 - bf2f(h0)), l1 = bbits(v1 - bf2f(h1));
      u16 l2 = bbits(v2 - bf2f(h2)), l3 = bbits(v3 - bf2f(h3));
      uint2v hv, lv;
      hv.x = (unsigned)h0 | ((unsigned)h1 << 16);
      hv.y = (unsigned)h2 | ((unsigned)h3 << 16);
      lv.x = (unsigned)l0 | ((unsigned)l1 << 16);
      lv.y = (unsigned)l2 | ((unsigned)l3 << 16);
      *reinterpret_cast<uint2v*>(Hi + p * 64 + chb) = hv;
      *reinterpret_cast<uint2v*>(Lo + p * 64 + chb) = lv;
    }
  }
}

__global__ __launch_bounds__(128) void pa_proj(
    const float* __restrict__ H, const float* __restrict__ L,
    const float* __restrict__ tb, const float* __restrict__ pb, const float* __restrict__ gb,
    const u16* __restrict__ Wth, const u16* __restrict__ Wtl,
    const u16* __restrict__ Wph, const u16* __restrict__ Wpl,
    const u16* __restrict__ Wgh, const u16* __restrict__ Wgl,
    u16* __restrict__ Qh, u16* __restrict__ Ql,
    u16* __restrict__ Kh, u16* __restrict__ Kl, u16* __restrict__ V) {
  int b = blockIdx.x >> 6;
  int tile = blockIdx.x & 63;
  int w = threadIdx.x >> 6;
  int lane = threadIdx.x & 63;
  int l31 = lane & 31, q2 = lane >> 5;
  int n0 = tile * 64 + w * 32;
  int p0 = b * 4096 + n0;
  int n = n0 + l31;

  // Build X B-fragments (hi/lo) for k-steps 0..7 (128 HL channels)
  bf16x8 Bh[8], Bl[8];
#pragma unroll
  for (int s = 0; s < 8; ++s) {
    const float* src = (s < 4) ? (H + (b * 64 + s * 16) * 4096) : (L + (b * 64 + (s - 4) * 16) * 4096);
    const float* pp = src + (q2 * 8) * 4096 + n;
    float xv[8];
#pragma unroll
    for (int j = 0; j < 8; ++j) xv[j] = pp[j * 4096];
    split8(xv, Bh[s], Bl[s]);
  }

  // theta -> K
  {
    f32x16 a0 = {}, a1 = {};
#pragma unroll
    for (int s = 0; s < 8; ++s) {
      int ko = s * 16 + q2 * 8;
      bf16x8 w0h = ldg16(Wth + l31 * 128 + ko);
      bf16x8 w0l = ldg16(Wtl + l31 * 128 + ko);
      bf16x8 w1h = ldg16(Wth + (32 + l31) * 128 + ko);
      bf16x8 w1l = ldg16(Wtl + (32 + l31) * 128 + ko);
      a0 = MFMA32(w0h, Bh[s], a0);
      a0 = MFMA32(w0h, Bl[s], a0);
      a0 = MFMA32(w0l, Bh[s], a0);
      a1 = MFMA32(w1h, Bh[s], a1);
      a1 = MFMA32(w1h, Bl[s], a1);
      a1 = MFMA32(w1l, Bh[s], a1);
    }
    store_qk(a0, a1, tb, Kh, Kl, p0 + l31, q2);
  }
  // phi -> Q
  {
    f32x16 a0 = {}, a1 = {};
#pragma unroll
    for (int s = 0; s < 8; ++s) {
      int ko = s * 16 + q2 * 8;
      bf16x8 w0h = ldg16(Wph + l31 * 128 + ko);
      bf16x8 w0l = ldg16(Wpl + l31 * 128 + ko);
      bf16x8 w1h = ldg16(Wph + (32 + l31) * 128 + ko);
      bf16x8 w1l = ldg16(Wpl + (32 + l31) * 128 + ko);
      a0 = MFMA32(w0h, Bh[s], a0);
      a0 = MFMA32(w0h, Bl[s], a0);
      a0 = MFMA32(w0l, Bh[s], a0);
      a1 = MFMA32(w1h, Bh[s], a1);
      a1 = MFMA32(w1h, Bl[s], a1);
      a1 = MFMA32(w1l, Bh[s], a1);
    }
    store_qk(a0, a1, pb, Qh, Ql, p0 + l31, q2);
  }
  // g -> V  (L channels only: k-steps 4..7)
  {
    f32x16 a0 = {}, a1 = {};
#pragma unroll
    for (int s = 4; s < 8; ++s) {
      int ko = (s - 4) * 16 + q2 * 8;
      bf16x8 w0h = ldg16(Wgh + l31 * 64 + ko);
      bf16x8 w0l = ldg16(Wgl + l31 * 64 + ko);
      bf16x8 w1h = ldg16(Wgh + (32 + l31) * 64 + ko);
      bf16x8 w1l = ldg16(Wgl + (32 + l31) * 64 + ko);
      a0 = MFMA32(w0h, Bh[s], a0);
      a0 = MFMA32(w0h, Bl[s], a0);
      a0 = MFMA32(w0l, Bh[s], a0);
      a1 = MFMA32(w1h, Bh[s], a1);
      a1 = MFMA32(w1h, Bl[s], a1);
      a1 = MFMA32(w1l, Bh[s], a1);
    }
#pragma unroll
    for (int mt = 0; mt < 2; ++mt) {
      const f32x16& A = mt ? a1 : a0;
#pragma unroll
      for (int rq = 0; rq < 4; ++rq) {
        int chb = mt * 32 + rq * 8 + q2 * 4;
        float4 bb = *reinterpret_cast<const float4*>(gb + chb);
        float v0 = A[rq * 4 + 0] + bb.x;
        float v1 = A[rq * 4 + 1] + bb.y;
        float v2 = A[rq * 4 + 2] + bb.z;
        float v3 = A[rq * 4 + 3] + bb.w;
        V[(b * 64 + chb + 0) * 4096 + n] = bbits(v0);
        V[(b * 64 + chb + 1) * 4096 + n] = bbits(v1);
        V[(b * 64 + chb + 2) * 4096 + n] = bbits(v2);
        V[(b * 64 + chb + 3) * 4096 + n] = bbits(v3);
      }
    }
  }
}

// ---------------------------------------------------------------------------
// Flash attention: O^T[c,m] = sum_n softmax_n(K[n,:]·Q[m,:]) * V[c,n]
// Block = (b, row y): m-tile 64. 4 waves split n 4-way (stride-interleaved
// 32-key tiles), private online-softmax state, merged via LDS at the end.
// mfma 32x32x16 bf16. QK in hi/lo split (3 mfma) for fp32-grade logits.
// A-frag: row=lane&31, k=(lane>>5)*8+j. B-frag: col=lane&31, k=(lane>>5)*8+j.
// C/D: col=lane&31, row=(r&3)+8*(r>>2)+4*(lane>>5).
// No __syncthreads in the K-loop (K/Q/V frags direct from global/L2; the
// only LDS use is the wave-private P C-layout->B-layout round trip).
// ---------------------------------------------------------------------------
__global__ __launch_bounds__(256, 1) void pa_flash(
    const u16* __restrict__ Qh, const u16* __restrict__ Ql,
    const u16* __restrict__ Kh, const u16* __restrict__ Kl,
    const u16* __restrict__ V, u16* __restrict__ E) {
  __shared__ u16 Pbuf[4][64 * 36];  // per-wave P, row stride 36 (2-way banks, 8B aligned)
  __shared__ float Obuf[64 * 67];   // merge buffer [c][m], stride 67
  __shared__ float MLm[4][2][32];
  __shared__ float MLl[4][2][32];
  __shared__ float Lstar[64];

  int tid = threadIdx.x;
  int w = tid >> 6, lane = tid & 63;
  int l31 = lane & 31, q2 = lane >> 5;
  int blk = blockIdx.x;
  int b = blk >> 6, y = blk & 63;
  int m0 = y * 64;
  int bq = b * 4096;

  // Q fragments (held in registers for the whole kernel): B-operand layout
  bf16x8 qh[2][4], ql[2][4];
#pragma unroll
  for (int mb = 0; mb < 2; ++mb)
#pragma unroll
    for (int kc = 0; kc < 4; ++kc) {
      int idx = (bq + m0 + mb * 32 + l31) * 64 + kc * 16 + q2 * 8;
      qh[mb][kc] = ldg16(Qh + idx);
      ql[mb][kc] = ldg16(Ql + idx);
    }

  f32x16 accO[2][2] = {};          // [cb][mb], C layout: row=c, col=m
  float Mm[2] = {-1e30f, -1e30f};  // running max per m-column (mb 0/1)
  float Ll[2] = {0.f, 0.f};        // running sum
  u16* mypb = &Pbuf[w][0];

#pragma unroll 1
  for (int it = 0; it < 32; ++it) {
    int n0 = it * 128 + w * 32;  // this wave's 32-key tile

    bf16x8 kh[4], kl[4];
#pragma unroll
    for (int kc = 0; kc < 4; ++kc) {
      int idx = (bq + n0 + l31) * 64 + kc * 16 + q2 * 8;
      kh[kc] = ldg16(Kh + idx);
      kl[kc] = ldg16(Kl + idx);
    }
    bf16x8 vf[2][2];
#pragma unroll
    for (int cbi = 0; cbi < 2; ++cbi)
#pragma unroll
      for (int kch = 0; kch < 2; ++kch)
        vf[cbi][kch] = ldg16(V + (b * 64 + cbi * 32 + l31) * 4096 + n0 + kch * 16 + q2 * 8);

    // S^T = K · Q^T with hi/lo split (drop kl*ql); two partial accs -> depth-6 chains
    f32x16 sA[2], sB[2];
#pragma unroll
    for (int mb = 0; mb < 2; ++mb) {
      f32x16 a = {};
      f32x16 b2 = {};
#pragma unroll
      for (int kc = 0; kc < 2; ++kc) {
        a = MFMA32(kh[kc], qh[mb][kc], a);
        a = MFMA32(kh[kc], ql[mb][kc], a);
        a = MFMA32(kl[kc], qh[mb][kc], a);
      }
#pragma unroll
      for (int kc = 2; kc < 4; ++kc) {
        b2 = MFMA32(kh[kc], qh[mb][kc], b2);
        b2 = MFMA32(kh[kc], ql[mb][kc], b2);
        b2 = MFMA32(kl[kc], qh[mb][kc], b2);
      }
      sA[mb] = a;
      sB[mb] = b2;
    }

    // online softmax (per m-column; lane holds 16 of the 32 n's, partner via xor-32)
#pragma unroll
    for (int mb = 0; mb < 2; ++mb) {
      float s[16];
#pragma unroll
      for (int r = 0; r < 16; ++r) s[r] = sA[mb][r] + sB[mb][r];
      float tmax = s[0];
#pragma unroll
      for (int r = 1; r < 16; ++r) tmax = fmaxf(tmax, s[r]);
      tmax = fmaxf(tmax, __shfl_xor(tmax, 32, 64));
      float newM = fmaxf(Mm[mb], tmax);
      float alpha = __expf(Mm[mb] - newM);
      Mm[mb] = newM;
      float pv[16];
      float psum = 0.f;
#pragma unroll
      for (int r = 0; r < 16; ++r) {
        pv[r] = __expf(s[r] - newM);
        psum += pv[r];
      }
      psum += __shfl_xor(psum, 32, 64);
      Ll[mb] = Ll[mb] * alpha + psum;
#pragma unroll
      for (int r = 0; r < 16; ++r) {
        accO[0][mb][r] *= alpha;
        accO[1][mb][r] *= alpha;
      }
      // P: C-layout regs -> LDS [m][n] (B-operand layout for PV). 4 consec n per reg-quad.
      u16* prow = mypb + (mb * 32 + l31) * 36;
#pragma unroll
      for (int rq = 0; rq < 4; ++rq) {
        unsigned lo = (unsigned)bbits(pv[rq * 4 + 0]) | ((unsigned)bbits(pv[rq * 4 + 1]) << 16);
        unsigned hi = (unsigned)bbits(pv[rq * 4 + 2]) | ((unsigned)bbits(pv[rq * 4 + 3]) << 16);
        uint2v uu;
        uu.x = lo;
        uu.y = hi;
        *reinterpret_cast<uint2v*>(prow + rq * 8 + q2 * 4) = uu;  // n = 8*rq + 4*q2 + 0..3
      }
    }

    // PV: O^T += V^T(A) · P^T(B)
#pragma unroll
    for (int mb = 0; mb < 2; ++mb) {
      const u16* prow = mypb + (mb * 32 + l31) * 36;
      bf16x8 p0 = ld_p8(prow + q2 * 8);       // k = n 0..15
      bf16x8 p1 = ld_p8(prow + 16 + q2 * 8);  // k = n 16..31
      accO[0][mb] = MFMA32(vf[0][0], p0, accO[0][mb]);
      accO[0][mb] = MFMA32(vf[0][1], p1, accO[0][mb]);
      accO[1][mb] = MFMA32(vf[1][0], p0, accO[1][mb]);
      accO[1][mb] = MFMA32(vf[1][1], p1, accO[1][mb]);
    }
  }

  // ---- merge the 4 waves' partial (O, M, l) ----
  if (q2 == 0) {
#pragma unroll
    for (int mb = 0; mb < 2; ++mb) {
      MLm[w][mb][l31] = Mm[mb];
      MLl[w][mb][l31] = Ll[mb];
    }
  }
  __syncthreads();
  float mysc[2];
#pragma unroll
  for (int mb = 0; mb < 2; ++mb) {
    float M = MLm[0][mb][l31];
    for (int ww = 1; ww < 4; ++ww) M = fmaxf(M, MLm[ww][mb][l31]);
    float ls = 0.f;
    for (int ww = 0; ww < 4; ++ww) ls += MLl[ww][mb][l31] * __expf(MLm[ww][mb][l31] - M);
    mysc[mb] = __expf(Mm[mb] - M);
    if (w == 0 && q2 == 0) Lstar[mb * 32 + l31] = ls;
  }
  for (int ww = 0; ww < 4; ++ww) {
    if (w == ww) {
#pragma unroll
      for (int cbi = 0; cbi < 2; ++cbi)
#pragma unroll
        for (int mb = 0; mb < 2; ++mb) {
          float sc = mysc[mb];
#pragma unroll
          for (int r = 0; r < 16; ++r) {
            int c = cbi * 32 + (r & 3) + 8 * (r >> 2) + 4 * q2;
            int m = mb * 32 + l31;
            float* dst = &Obuf[c * 67 + m];
            float v = accO[cbi][mb][r] * sc;
            if (ww == 0)
              *dst = v;
            else
              *dst += v;
          }
        }
    }
    __syncthreads();
  }
  // write E[b][m][c] bf16 (spatial-major for the conv's B-operand)
  int em = tid >> 2, ec0 = (tid & 3) * 16;
  float invl = 1.0f / Lstar[em];
  float vals[16];
#pragma unroll
  for (int j = 0; j < 16; ++j) vals[j] = Obuf[(ec0 + j) * 67 + em] * invl;
  uint4v u0, u1;
  u0.x = (unsigned)bbits(vals[0]) | ((unsigned)bbits(vals[1]) << 16);
  u0.y = (unsigned)bbits(vals[2]) | ((unsigned)bbits(vals[3]) << 16);
  u0.z = (unsigned)bbits(vals[4]) | ((unsigned)bbits(vals[5]) << 16);
  u0.w = (unsigned)bbits(vals[6]) | ((unsigned)bbits(vals[7]) << 16);
  u1.x = (unsigned)bbits(vals[8]) | ((unsigned)bbits(vals[9]) << 16);
  u1.y = (unsigned)bbits(vals[10]) | ((unsigned)bbits(vals[11]) << 16);
  u1.z = (unsigned)bbits(vals[12]) | ((unsigned)bbits(vals[13]) << 16);
  u1.w = (unsigned)bbits(vals[14]) | ((unsigned)bbits(vals[15]) << 16);
  u16* ep = E + (bq + m0 + em) * 64 + ec0;
  *reinterpret_cast<uint4v*>(ep) = u0;
  *reinterpret_cast<uint4v*>(ep + 8) = u1;
}

// ---------------------------------------------------------------------------
// Conv3x3(SAME)+BN+ReLU+residual as 9 shifted MFMA GEMMs.
// Block = (b, row y). LDS holds rows y-1..y+1 with x-halo, [x+1][c] stride 68.
// ---------------------------------------------------------------------------
__global__ __launch_bounds__(256) void pa_conv(
    const u16* __restrict__ E, const u16* __restrict__ Wt,
    const float* __restrict__ bnA, const float* __restrict__ bnB,
    const float* __restrict__ H, float* __restrict__ out) {
  __shared__ u16 Er[3][66 * 68];
  int tid = threadIdx.x;
  int blk = blockIdx.x;
  int b = blk >> 6, y = blk & 63;
  int lane = tid & 63;
  int l31 = lane & 31, q2 = lane >> 5;
  int wv = tid >> 6;
  int cbi = wv >> 1, mb = wv & 1;
  int s0 = (y == 0) ? 1 : 0;
  int s1 = (y == 63) ? 1 : 2;

  for (int s = s0; s <= s1; ++s) {
    int yy = y + s - 1;
#pragma unroll
    for (int rep = 0; rep < 2; ++rep) {
      int id = rep * 256 + tid;
      int x = id >> 3, co = (id & 7) * 8;
      const uint2v* src = reinterpret_cast<const uint2v*>(E + ((b * 4096 + yy * 64 + x) * 64 + co));
      uint2v a = src[0], b4 = src[1];
      u16* d = &Er[s][(x + 1) * 68 + co];
      *reinterpret_cast<uint2v*>(d) = a;
      *reinterpret_cast<uint2v*>(d + 4) = b4;
    }
  }
  if (tid < 96) {  // zero x-halo columns
    int s = tid >> 5, side = (tid >> 4) & 1, co = (tid & 15) * 4;
    uint2v z;
    z.x = 0;
    z.y = 0;
    *reinterpret_cast<uint2v*>(&Er[s][(side ? 65 : 0) * 68 + co]) = z;
  }
  __syncthreads();

  f32x16 acc = {};
  for (int s = s0; s <= s1; ++s) {
#pragma unroll
    for (int dx = 0; dx < 3; ++dx)
#pragma unroll
      for (int kc = 0; kc < 4; ++kc) {
        bf16x8 a = ldg16(Wt + ((s * 3 + dx) * 64 + cbi * 32 + l31) * 64 + kc * 16 + q2 * 8);
        const u16* pbr = &Er[s][(mb * 32 + l31 + dx) * 68 + kc * 16 + q2 * 8];
        bf16x8 bb = ld_p8(pbr);
        acc = MFMA32(a, bb, acc);
      }
  }
#pragma unroll
  for (int r = 0; r < 16; ++r) {
    int c = cbi * 32 + (r & 3) + 8 * (r >> 2) + 4 * q2;
    int x = mb * 32 + l31;
    float v = acc[r] * bnA[c] + bnB[c];
    v = fmaxf(v, 0.f);
    int idx = ((b * 64 + c) * 64 + y) * 64 + x;
    out[idx] = H[idx] + v;
  }
}

// ---------------------------------------------------------------------------
extern "C" void kernel_launch(void* const* d_in, const int* in_sizes, int n_in,
                              void* d_out, int out_size, void* d_ws, size_t ws_size,
                              hipStream_t stream) {
  (void)in_sizes; (void)n_in; (void)out_size; (void)ws_size;
  const float* H = (const float*)d_in[0];
  const float* L = (const float*)d_in[1];
  const float* tw = (const float*)d_in[2];
  const float* tb = (const float*)d_in[3];
  const float* pw = (const float*)d_in[4];
  const float* pb = (const float*)d_in[5];
  const float* gw = (const float*)d_in[6];
  const float* gb = (const float*)d_in[7];
  const float* cw = (const float*)d_in[8];
  const float* cb = (const float*)d_in[9];
  const float* gamma = (const float*)d_in[10];
  const float* beta = (const float*)d_in[11];
  const float* mean = (const float*)d_in[12];
  const float* var = (const float*)d_in[13];

  const int NC = 16384 * 64;  // 1M elements per [b][n][c] plane
  u16* Qh = (u16*)d_ws;
  u16* Ql = Qh + NC;
  u16* Kh = Ql + NC;
  u16* Kl = Kh + NC;
  u16* Vv = Kl + NC;
  u16* Eb = Vv + NC;
  u16* Wt = Eb + NC;                       // 36864 u16
  float* bnA = (float*)(Wt + 36864);       // 64 f32
  float* bnB = bnA + 64;                   // 64 f32
  u16* Wth = (u16*)(bnB + 64);             // 8192 u16 each below
  u16* Wtl = Wth + 8192;
  u16* Wph = Wtl + 8192;
  u16* Wpl = Wph + 8192;
  u16* Wgh = Wpl + 8192;                   // 4096
  u16* Wgl = Wgh + 4096;                   // 4096

  pa_prep<<<144, 256, 0, stream>>>(cw, cb, gamma, beta, mean, var, tw, pw, gw,
                                   Wt, bnA, bnB, Wth, Wtl, Wph, Wpl, Wgh, Wgl);
  pa_proj<<<256, 128, 0, stream>>>(H, L, tb, pb, gb, Wth, Wtl, Wph, Wpl, Wgh, Wgl,
                                   Qh, Ql, Kh, Kl, Vv);
  pa_flash<<<256, 256, 0, stream>>>(Qh, Ql, Kh, Kl, Vv, Eb);
  pa_conv<<<256, 256, 0, stream>>>(Eb, Wt, bnA, bnB, H, (float*)d_out);
}

// Round 4
// 158.015 us; speedup vs baseline: 1.6139x; 1.1342x over previous
//
#include <hip/hip_runtime.h>

typedef __bf16 bf16;
typedef unsigned short u16;
typedef __attribute__((ext_vector_type(8))) __bf16 bf16x8;
typedef __attribute__((ext_vector_type(16))) float f32x16;
typedef __attribute__((ext_vector_type(2))) unsigned int uint2v;
typedef __attribute__((ext_vector_type(4))) unsigned int uint4v;

#define MFMA32(a, b, c) __builtin_amdgcn_mfma_f32_32x32x16_bf16(a, b, c, 0, 0, 0)

__device__ __forceinline__ u16 bbits(float f) {
  bf16 h = (bf16)f;
  return __builtin_bit_cast(u16, h);
}
__device__ __forceinline__ float bf2f(u16 u) {
  return (float)__builtin_bit_cast(bf16, u);
}
__device__ __forceinline__ bf16x8 ldg16(const u16* p) {
  return *reinterpret_cast<const bf16x8*>(p);  // 16B-aligned by construction
}
// 8-byte-aligned read of 8 bf16 as two b64s (for 8B-aligned LDS rows)
__device__ __forceinline__ bf16x8 ld_p8(const u16* p) {
  uint2v a = *reinterpret_cast<const uint2v*>(p);
  uint2v b = *reinterpret_cast<const uint2v*>(p + 4);
  uint4v u;
  u.x = a.x; u.y = a.y; u.z = b.x; u.w = b.y;
  return __builtin_bit_cast(bf16x8, u);
}
// split 8 fp32 into hi/lo bf16x8 fragments
__device__ __forceinline__ void split8(const float* xv, bf16x8& hi, bf16x8& lo) {
  uint4v hv, lv;
#pragma unroll
  for (int jp = 0; jp < 4; ++jp) {
    float a0 = xv[2 * jp], a1 = xv[2 * jp + 1];
    u16 h0 = bbits(a0), h1 = bbits(a1);
    u16 l0 = bbits(a0 - bf2f(h0)), l1 = bbits(a1 - bf2f(h1));
    unsigned hh = (unsigned)h0 | ((unsigned)h1 << 16);
    unsigned ll = (unsigned)l0 | ((unsigned)l1 << 16);
    if (jp == 0) { hv.x = hh; lv.x = ll; }
    else if (jp == 1) { hv.y = hh; lv.y = ll; }
    else if (jp == 2) { hv.z = hh; lv.z = ll; }
    else { hv.w = hh; lv.w = ll; }
  }
  hi = __builtin_bit_cast(bf16x8, hv);
  lo = __builtin_bit_cast(bf16x8, lv);
}

// ---------------------------------------------------------------------------
// Prep: conv weights -> Wt[dy*3+dx][c_out][c_in] bf16; BN folded: out = A*conv+B
// Also: theta/phi/g 1x1 weights -> hi/lo bf16 [out][in] for MFMA A-fragments.
// ---------------------------------------------------------------------------
__global__ __launch_bounds__(256) void pa_prep(
    const float* __restrict__ cw, const float* __restrict__ cbias,
    const float* __restrict__ gamma, const float* __restrict__ beta,
    const float* __restrict__ mean, const float* __restrict__ var,
    const float* __restrict__ tw, const float* __restrict__ pw, const float* __restrict__ gw,
    u16* __restrict__ Wt, float* __restrict__ bnA, float* __restrict__ bnB,
    u16* __restrict__ Wth, u16* __restrict__ Wtl,
    u16* __restrict__ Wph, u16* __restrict__ Wpl,
    u16* __restrict__ Wgh, u16* __restrict__ Wgl) {
  int i = blockIdx.x * 256 + threadIdx.x;
  if (i < 36864) {
    int ci = i & 63, co = (i >> 6) & 63, s = i >> 12;  // s = dy*3+dx
    Wt[(s * 64 + co) * 64 + ci] = bbits(cw[(co * 64 + ci) * 9 + s]);
  }
  if (i < 8192) {
    float v = tw[i];
    u16 h = bbits(v);
    Wth[i] = h;
    Wtl[i] = bbits(v - bf2f(h));
  } else if (i < 16384) {
    int j = i - 8192;
    float v = pw[j];
    u16 h = bbits(v);
    Wph[j] = h;
    Wpl[j] = bbits(v - bf2f(h));
  } else if (i < 20480) {
    int j = i - 16384;
    float v = gw[j];
    u16 h = bbits(v);
    Wgh[j] = h;
    Wgl[j] = bbits(v - bf2f(h));
  }
  if (i < 64) {
    float rs = rsqrtf(var[i] + 1e-5f);
    float A = gamma[i] * rs;
    bnA[i] = A;
    bnB[i] = (cbias[i] - mean[i]) * A + beta[i];
  }
}

// ---------------------------------------------------------------------------
// Projections as MFMA GEMM, role-split across 6 waves per block:
// waves 0,1 theta->K | 2,3 phi->Q | 4,5 g->V. Each wave owns 32 positions.
// 1536 waves total (1.5/SIMD) vs round-3's 512 (0.5/SIMD).
// Hi/lo bf16 split on W and X (3 MFMA/product) => fp32-grade precision.
// ---------------------------------------------------------------------------
__device__ __forceinline__ void store_qk(const f32x16& a0, const f32x16& a1,
                                         const float* __restrict__ bias,
                                         u16* __restrict__ Hi, u16* __restrict__ Lo,
                                         int p, int q2) {
#pragma unroll
  for (int mt = 0; mt < 2; ++mt) {
    const f32x16& A = mt ? a1 : a0;
#pragma unroll
    for (int rq = 0; rq < 4; ++rq) {
      int chb = mt * 32 + rq * 8 + q2 * 4;
      float4 bb = *reinterpret_cast<const float4*>(bias + chb);
      float v0 = A[rq * 4 + 0] + bb.x;
      float v1 = A[rq * 4 + 1] + bb.y;
      float v2 = A[rq * 4 + 2] + bb.z;
      float v3 = A[rq * 4 + 3] + bb.w;
      u16 h0 = bbits(v0), h1 = bbits(v1), h2 = bbits(v2), h3 = bbits(v3);
      u16 l0 = bbits(v0 - bf2f(h0)), l1 = bbits(v1 - bf2f(h1));
      u16 l2 = bbits(v2 - bf2f(h2)), l3 = bbits(v3 - bf2f(h3));
      uint2v hv, lv;
      hv.x = (unsigned)h0 | ((unsigned)h1 << 16);
      hv.y = (unsigned)h2 | ((unsigned)h3 << 16);
      lv.x = (unsigned)l0 | ((unsigned)l1 << 16);
      lv.y = (unsigned)l2 | ((unsigned)l3 << 16);
      *reinterpret_cast<uint2v*>(Hi + p * 64 + chb) = hv;
      *reinterpret_cast<uint2v*>(Lo + p * 64 + chb) = lv;
    }
  }
}

template <int NS, int STR>
__device__ __forceinline__ void gemm3(const u16* __restrict__ Wh, const u16* __restrict__ Wl,
                                      const bf16x8* Bh, const bf16x8* Bl,
                                      int l31, int q2, f32x16& a0, f32x16& a1) {
#pragma unroll
  for (int s = 0; s < NS; ++s) {
    int ko = s * 16 + q2 * 8;
    bf16x8 w0h = ldg16(Wh + l31 * STR + ko);
    bf16x8 w0l = ldg16(Wl + l31 * STR + ko);
    bf16x8 w1h = ldg16(Wh + (32 + l31) * STR + ko);
    bf16x8 w1l = ldg16(Wl + (32 + l31) * STR + ko);
    a0 = MFMA32(w0h, Bh[s], a0);
    a0 = MFMA32(w0h, Bl[s], a0);
    a0 = MFMA32(w0l, Bh[s], a0);
    a1 = MFMA32(w1h, Bh[s], a1);
    a1 = MFMA32(w1h, Bl[s], a1);
    a1 = MFMA32(w1l, Bh[s], a1);
  }
}

__global__ __launch_bounds__(384, 2) void pa_proj(
    const float* __restrict__ H, const float* __restrict__ L,
    const float* __restrict__ tb, const float* __restrict__ pb, const float* __restrict__ gb,
    const u16* __restrict__ Wth, const u16* __restrict__ Wtl,
    const u16* __restrict__ Wph, const u16* __restrict__ Wpl,
    const u16* __restrict__ Wgh, const u16* __restrict__ Wgl,
    u16* __restrict__ Qh, u16* __restrict__ Ql,
    u16* __restrict__ Kh, u16* __restrict__ Kl, u16* __restrict__ V) {
  int b = blockIdx.x >> 6;
  int tile = blockIdx.x & 63;
  int w = threadIdx.x >> 6;  // 0..5
  int lane = threadIdx.x & 63;
  int l31 = lane & 31, q2 = lane >> 5;
  int half = w & 1, role = w >> 1;  // 0 theta, 1 phi, 2 g
  int n0 = tile * 64 + half * 32;
  int n = n0 + l31;
  int p0 = b * 4096 + n0;

  if (role < 2) {
    bf16x8 Bh[8], Bl[8];
#pragma unroll
    for (int s = 0; s < 8; ++s) {
      const float* src = (s < 4) ? (H + (b * 64 + s * 16) * 4096)
                                 : (L + (b * 64 + (s - 4) * 16) * 4096);
      const float* pp = src + (q2 * 8) * 4096 + n;
      float xv[8];
#pragma unroll
      for (int j = 0; j < 8; ++j) xv[j] = pp[j * 4096];
      split8(xv, Bh[s], Bl[s]);
    }
    const u16* Wh = role ? Wph : Wth;
    const u16* Wl = role ? Wpl : Wtl;
    const float* bias = role ? pb : tb;
    u16* Oh = role ? Qh : Kh;  // theta -> keys K, phi -> queries Q
    u16* Ol = role ? Ql : Kl;
    f32x16 a0 = {}, a1 = {};
    gemm3<8, 128>(Wh, Wl, Bh, Bl, l31, q2, a0, a1);
    store_qk(a0, a1, bias, Oh, Ol, p0 + l31, q2);
  } else {
    bf16x8 Bh[4], Bl[4];
#pragma unroll
    for (int s = 0; s < 4; ++s) {
      const float* pp = L + (b * 64 + s * 16 + q2 * 8) * 4096 + n;
      float xv[8];
#pragma unroll
      for (int j = 0; j < 8; ++j) xv[j] = pp[j * 4096];
      split8(xv, Bh[s], Bl[s]);
    }
    f32x16 a0 = {}, a1 = {};
    gemm3<4, 64>(Wgh, Wgl, Bh, Bl, l31, q2, a0, a1);
#pragma unroll
    for (int mt = 0; mt < 2; ++mt) {
      const f32x16& A = mt ? a1 : a0;
#pragma unroll
      for (int rq = 0; rq < 4; ++rq) {
        int chb = mt * 32 + rq * 8 + q2 * 4;
        float4 bb = *reinterpret_cast<const float4*>(gb + chb);
        V[(b * 64 + chb + 0) * 4096 + n] = bbits(A[rq * 4 + 0] + bb.x);
        V[(b * 64 + chb + 1) * 4096 + n] = bbits(A[rq * 4 + 1] + bb.y);
        V[(b * 64 + chb + 2) * 4096 + n] = bbits(A[rq * 4 + 2] + bb.z);
        V[(b * 64 + chb + 3) * 4096 + n] = bbits(A[rq * 4 + 3] + bb.w);
      }
    }
  }
}

// ---------------------------------------------------------------------------
// Flash attention: O^T[c,m] = sum_n softmax_n(K[n,:]·Q[m,:]) * V[c,n]
// Block = (b, y): m-tile 64. 512 threads = 8 waves (2/SIMD) splitting n
// 8-way, 16 iters of 32 keys each. K double-buffer prefetched one iter
// ahead; V issued ~700cyc before use. Q fragments live in LDS (block-
// shared, stride 68 -> 2-way-free banks). FIXED-M softmax: M frozen after
// each wave's first tile (exact in fp32; exp headroom e^88 >> logit
// spread), so no per-iter rescale of accO. Exact max-merge across 8 waves
// at the end; merge buffers overlay Pbuf.
// C/D layout: col=lane&31 (m), row=(r&3)+8*(r>>2)+4*(lane>>5) (key n).
// ---------------------------------------------------------------------------
__global__ __launch_bounds__(512, 2) void pa_flash(
    const u16* __restrict__ Qh, const u16* __restrict__ Ql,
    const u16* __restrict__ Kh, const u16* __restrict__ Kl,
    const u16* __restrict__ V, u16* __restrict__ E) {
  __shared__ __align__(16) char smem[54272];
  u16* Pb = (u16*)smem;              // [8][64*36] u16, loop phase
  u16* Qld = (u16*)(smem + 36864);   // hi [64][68], lo at +4352 u16
  // post-loop overlay (first region):
  float* Obuf = (float*)smem;            // 64*67 f32
  float* MLm = (float*)(smem + 17152);   // [8][2][32]
  float* MLl = (float*)(smem + 19200);   // [8][2][32]
  float* Lst = (float*)(smem + 21248);   // [64]

  int tid = threadIdx.x;
  int w = tid >> 6, lane = tid & 63;
  int l31 = lane & 31, q2 = lane >> 5;
  int b = blockIdx.x >> 6, y = blockIdx.x & 63;
  int m0 = y * 64;
  int bq = b * 4096;

  // ---- stage Q tile (hi+lo) into LDS, block-cooperative ----
  {
    int m = tid >> 3, c0 = (tid & 7) * 8;
    int gidx = (bq + m0 + m) * 64 + c0;
    bf16x8 vh = ldg16(Qh + gidx);
    bf16x8 vl = ldg16(Ql + gidx);
    uint4v uh = __builtin_bit_cast(uint4v, vh);
    uint4v ul = __builtin_bit_cast(uint4v, vl);
    u16* dh = Qld + m * 68 + c0;
    uint2v t0; t0.x = uh.x; t0.y = uh.y;
    uint2v t1; t1.x = uh.z; t1.y = uh.w;
    *reinterpret_cast<uint2v*>(dh) = t0;
    *reinterpret_cast<uint2v*>(dh + 4) = t1;
    u16* dl = Qld + 4352 + m * 68 + c0;
    uint2v t2; t2.x = ul.x; t2.y = ul.y;
    uint2v t3; t3.x = ul.z; t3.y = ul.w;
    *reinterpret_cast<uint2v*>(dl) = t2;
    *reinterpret_cast<uint2v*>(dl + 4) = t3;
  }
  __syncthreads();

  f32x16 accO[2][2] = {};  // [cb][mb], C layout: row=c, col=m
  float Mm[2] = {0.f, 0.f};
  float Ll[2] = {0.f, 0.f};
  u16* mypb = Pb + w * (64 * 36);

  // K double-buffer: preload tile 0
  bf16x8 khb[2][4], klb[2][4];
#pragma unroll
  for (int kc = 0; kc < 4; ++kc) {
    int idx = (bq + w * 32 + l31) * 64 + kc * 16 + q2 * 8;
    khb[0][kc] = ldg16(Kh + idx);
    klb[0][kc] = ldg16(Kl + idx);
  }

#pragma unroll 2
  for (int it = 0; it < 16; ++it) {
    int cur = it & 1, nxt = cur ^ 1;
    int n0 = it * 256 + w * 32;
    int n0n = ((it < 15) ? (it + 1) : it) * 256 + w * 32;

    // prefetch next K tile
#pragma unroll
    for (int kc = 0; kc < 4; ++kc) {
      int idx = (bq + n0n + l31) * 64 + kc * 16 + q2 * 8;
      khb[nxt][kc] = ldg16(Kh + idx);
      klb[nxt][kc] = ldg16(Kl + idx);
    }
    // V for current tile (used ~end of iter)
    bf16x8 vf[2][2];
#pragma unroll
    for (int cbi = 0; cbi < 2; ++cbi)
#pragma unroll
      for (int kch = 0; kch < 2; ++kch)
        vf[cbi][kch] = ldg16(V + (b * 64 + cbi * 32 + l31) * 4096 + n0 + kch * 16 + q2 * 8);

#pragma unroll
    for (int mb = 0; mb < 2; ++mb) {
      // QK: S^T = K·Q^T, hi/lo split (two partial chains)
      f32x16 a = {}, b2 = {};
#pragma unroll
      for (int kc = 0; kc < 2; ++kc) {
        const u16* qrow = Qld + (mb * 32 + l31) * 68 + kc * 16 + q2 * 8;
        bf16x8 qh8 = ld_p8(qrow);
        bf16x8 ql8 = ld_p8(qrow + 4352);
        a = MFMA32(khb[cur][kc], qh8, a);
        a = MFMA32(khb[cur][kc], ql8, a);
        a = MFMA32(klb[cur][kc], qh8, a);
      }
#pragma unroll
      for (int kc = 2; kc < 4; ++kc) {
        const u16* qrow = Qld + (mb * 32 + l31) * 68 + kc * 16 + q2 * 8;
        bf16x8 qh8 = ld_p8(qrow);
        bf16x8 ql8 = ld_p8(qrow + 4352);
        b2 = MFMA32(khb[cur][kc], qh8, b2);
        b2 = MFMA32(khb[cur][kc], ql8, b2);
        b2 = MFMA32(klb[cur][kc], qh8, b2);
      }
      float sv[16];
#pragma unroll
      for (int r = 0; r < 16; ++r) sv[r] = a[r] + b2[r];
      if (it == 0) {  // freeze M from the wave's first tile (wave-uniform branch)
        float tmax = sv[0];
#pragma unroll
        for (int r = 1; r < 16; ++r) tmax = fmaxf(tmax, sv[r]);
        tmax = fmaxf(tmax, __shfl_xor(tmax, 32, 64));
        Mm[mb] = tmax;
      }
      float pv[16];
      float psum = 0.f;
#pragma unroll
      for (int r = 0; r < 16; ++r) {
        pv[r] = __expf(sv[r] - Mm[mb]);
        psum += pv[r];
      }
      psum += __shfl_xor(psum, 32, 64);
      Ll[mb] += psum;
      // P: C-layout regs -> LDS [m][n] (B-operand layout). 4 consec n per reg-quad.
      u16* prow = mypb + (mb * 32 + l31) * 36;
#pragma unroll
      for (int rq = 0; rq < 4; ++rq) {
        unsigned lo = (unsigned)bbits(pv[rq * 4 + 0]) | ((unsigned)bbits(pv[rq * 4 + 1]) << 16);
        unsigned hi = (unsigned)bbits(pv[rq * 4 + 2]) | ((unsigned)bbits(pv[rq * 4 + 3]) << 16);
        uint2v uu;
        uu.x = lo;
        uu.y = hi;
        *reinterpret_cast<uint2v*>(prow + rq * 8 + q2 * 4) = uu;  // n = 8*rq + 4*q2 + 0..3
      }
      // PV for this mb: O^T += V^T(A) · P^T(B)
      bf16x8 p0 = ld_p8(prow + q2 * 8);       // k = n 0..15
      bf16x8 p1 = ld_p8(prow + 16 + q2 * 8);  // k = n 16..31
      accO[0][mb] = MFMA32(vf[0][0], p0, accO[0][mb]);
      accO[0][mb] = MFMA32(vf[0][1], p1, accO[0][mb]);
      accO[1][mb] = MFMA32(vf[1][0], p0, accO[1][mb]);
      accO[1][mb] = MFMA32(vf[1][1], p1, accO[1][mb]);
    }
  }

  // ---- exact merge of 8 waves' (O, M, l); merge buffers overlay Pbuf ----
  __syncthreads();  // Pbuf reads done before overlay writes
  if (q2 == 0) {
#pragma unroll
    for (int mb = 0; mb < 2; ++mb) {
      MLm[(w * 2 + mb) * 32 + l31] = Mm[mb];
      MLl[(w * 2 + mb) * 32 + l31] = Ll[mb];
    }
  }
  __syncthreads();
  float mysc[2];
#pragma unroll
  for (int mb = 0; mb < 2; ++mb) {
    float M = MLm[(0 * 2 + mb) * 32 + l31];
    for (int ww = 1; ww < 8; ++ww) M = fmaxf(M, MLm[(ww * 2 + mb) * 32 + l31]);
    float ls = 0.f;
    for (int ww = 0; ww < 8; ++ww)
      ls += MLl[(ww * 2 + mb) * 32 + l31] * __expf(MLm[(ww * 2 + mb) * 32 + l31] - M);
    mysc[mb] = __expf(Mm[mb] - M);
    if (w == 0 && q2 == 0) Lst[mb * 32 + l31] = ls;
  }
  for (int ww = 0; ww < 8; ++ww) {
    if (w == ww) {
#pragma unroll
      for (int cbi = 0; cbi < 2; ++cbi)
#pragma unroll
        for (int mb = 0; mb < 2; ++mb) {
          float sc = mysc[mb];
#pragma unroll
          for (int r = 0; r < 16; ++r) {
            int c = cbi * 32 + (r & 3) + 8 * (r >> 2) + 4 * q2;
            int m = mb * 32 + l31;
            float* dst = &Obuf[c * 67 + m];
            float v = accO[cbi][mb][r] * sc;
            if (ww == 0)
              *dst = v;
            else
              *dst += v;
          }
        }
    }
    __syncthreads();
  }
  // write E[b][m][c] bf16 (spatial-major for the conv's B-operand)
  int em = tid >> 3, ec0 = (tid & 7) * 8;
  float invl = 1.0f / Lst[em];
  float vals[8];
#pragma unroll
  for (int j = 0; j < 8; ++j) vals[j] = Obuf[(ec0 + j) * 67 + em] * invl;
  uint4v u0;
  u0.x = (unsigned)bbits(vals[0]) | ((unsigned)bbits(vals[1]) << 16);
  u0.y = (unsigned)bbits(vals[2]) | ((unsigned)bbits(vals[3]) << 16);
  u0.z = (unsigned)bbits(vals[4]) | ((unsigned)bbits(vals[5]) << 16);
  u0.w = (unsigned)bbits(vals[6]) | ((unsigned)bbits(vals[7]) << 16);
  u16* ep = E + (bq + m0 + em) * 64 + ec0;
  *reinterpret_cast<uint4v*>(ep) = u0;
}

// ---------------------------------------------------------------------------
// Conv3x3(SAME)+BN+ReLU+residual as 9 shifted MFMA GEMMs.
// Block = (b, row y). LDS holds rows y-1..y+1 with x-halo, [x+1][c] stride 68.
// ---------------------------------------------------------------------------
__global__ __launch_bounds__(256) void pa_conv(
    const u16* __restrict__ E, const u16* __restrict__ Wt,
    const float* __restrict__ bnA, const float* __restrict__ bnB,
    const float* __restrict__ H, float* __restrict__ out) {
  __shared__ u16 Er[3][66 * 68];
  int tid = threadIdx.x;
  int blk = blockIdx.x;
  int b = blk >> 6, y = blk & 63;
  int lane = tid & 63;
  int l31 = lane & 31, q2 = lane >> 5;
  int wv = tid >> 6;
  int cbi = wv >> 1, mb = wv & 1;
  int s0 = (y == 0) ? 1 : 0;
  int s1 = (y == 63) ? 1 : 2;

  for (int s = s0; s <= s1; ++s) {
    int yy = y + s - 1;
#pragma unroll
    for (int rep = 0; rep < 2; ++rep) {
      int id = rep * 256 + tid;
      int x = id >> 3, co = (id & 7) * 8;
      const uint2v* src = reinterpret_cast<const uint2v*>(E + ((b * 4096 + yy * 64 + x) * 64 + co));
      uint2v a = src[0], b4 = src[1];
      u16* d = &Er[s][(x + 1) * 68 + co];
      *reinterpret_cast<uint2v*>(d) = a;
      *reinterpret_cast<uint2v*>(d + 4) = b4;
    }
  }
  if (tid < 96) {  // zero x-halo columns
    int s = tid >> 5, side = (tid >> 4) & 1, co = (tid & 15) * 4;
    uint2v z;
    z.x = 0;
    z.y = 0;
    *reinterpret_cast<uint2v*>(&Er[s][(side ? 65 : 0) * 68 + co]) = z;
  }
  __syncthreads();

  f32x16 acc = {};
  for (int s = s0; s <= s1; ++s) {
#pragma unroll
    for (int dx = 0; dx < 3; ++dx)
#pragma unroll
      for (int kc = 0; kc < 4; ++kc) {
        bf16x8 a = ldg16(Wt + ((s * 3 + dx) * 64 + cbi * 32 + l31) * 64 + kc * 16 + q2 * 8);
        const u16* pbr = &Er[s][(mb * 32 + l31 + dx) * 68 + kc * 16 + q2 * 8];
        bf16x8 bb = ld_p8(pbr);
        acc = MFMA32(a, bb, acc);
      }
  }
#pragma unroll
  for (int r = 0; r < 16; ++r) {
    int c = cbi * 32 + (r & 3) + 8 * (r >> 2) + 4 * q2;
    int x = mb * 32 + l31;
    float v = acc[r] * bnA[c] + bnB[c];
    v = fmaxf(v, 0.f);
    int idx = ((b * 64 + c) * 64 + y) * 64 + x;
    out[idx] = H[idx] + v;
  }
}

// ---------------------------------------------------------------------------
extern "C" void kernel_launch(void* const* d_in, const int* in_sizes, int n_in,
                              void* d_out, int out_size, void* d_ws, size_t ws_size,
                              hipStream_t stream) {
  (void)in_sizes; (void)n_in; (void)out_size; (void)ws_size;
  const float* H = (const float*)d_in[0];
  const float* L = (const float*)d_in[1];
  const float* tw = (const float*)d_in[2];
  const float* tb = (const float*)d_in[3];
  const float* pw = (const float*)d_in[4];
  const float* pb = (const float*)d_in[5];
  const float* gw = (const float*)d_in[6];
  const float* gb = (const float*)d_in[7];
  const float* cw = (const float*)d_in[8];
  const float* cb = (const float*)d_in[9];
  const float* gamma = (const float*)d_in[10];
  const float* beta = (const float*)d_in[11];
  const float* mean = (const float*)d_in[12];
  const float* var = (const float*)d_in[13];

  const int NC = 16384 * 64;  // 1M elements per [b][n][c] plane
  u16* Qh = (u16*)d_ws;
  u16* Ql = Qh + NC;
  u16* Kh = Ql + NC;
  u16* Kl = Kh + NC;
  u16* Vv = Kl + NC;
  u16* Eb = Vv + NC;
  u16* Wt = Eb + NC;                  // 36864 u16
  float* bnA = (float*)(Wt + 36864);  // 64 f32
  float* bnB = bnA + 64;              // 64 f32
  u16* Wth = (u16*)(bnB + 64);
  u16* Wtl = Wth + 8192;
  u16* Wph = Wtl + 8192;
  u16* Wpl = Wph + 8192;
  u16* Wgh = Wpl + 8192;  // 4096
  u16* Wgl = Wgh + 4096;  // 4096

  pa_prep<<<144, 256, 0, stream>>>(cw, cb, gamma, beta, mean, var, tw, pw, gw,
                                   Wt, bnA, bnB, Wth, Wtl, Wph, Wpl, Wgh, Wgl);
  pa_proj<<<256, 384, 0, stream>>>(H, L, tb, pb, gb, Wth, Wtl, Wph, Wpl, Wgh, Wgl,
                                   Qh, Ql, Kh, Kl, Vv);
  pa_flash<<<256, 512, 0, stream>>>(Qh, Ql, Kh, Kl, Vv, Eb);
  pa_conv<<<256, 256, 0, stream>>>(Eb, Wt, bnA, bnB, H, (float*)d_out);
}

// Round 5
// 133.405 us; speedup vs baseline: 1.9117x; 1.1845x over previous
//
#include <hip/hip_runtime.h>

typedef __bf16 bf16;
typedef unsigned short u16;
typedef __attribute__((ext_vector_type(8))) __bf16 bf16x8;
typedef __attribute__((ext_vector_type(16))) float f32x16;
typedef __attribute__((ext_vector_type(2))) unsigned int uint2v;
typedef __attribute__((ext_vector_type(4))) unsigned int uint4v;

#define MFMA32(a, b, c) __builtin_amdgcn_mfma_f32_32x32x16_bf16(a, b, c, 0, 0, 0)

__device__ __forceinline__ u16 bbits(float f) {
  bf16 h = (bf16)f;
  return __builtin_bit_cast(u16, h);
}
__device__ __forceinline__ float bf2f(u16 u) {
  return (float)__builtin_bit_cast(bf16, u);
}
__device__ __forceinline__ bf16x8 ldg16(const u16* p) {
  return *reinterpret_cast<const bf16x8*>(p);  // 16B-aligned by construction
}
// 8-byte-aligned read of 8 bf16 as two b64s (for 8B-aligned LDS rows)
__device__ __forceinline__ bf16x8 ld_p8(const u16* p) {
  uint2v a = *reinterpret_cast<const uint2v*>(p);
  uint2v b = *reinterpret_cast<const uint2v*>(p + 4);
  uint4v u;
  u.x = a.x; u.y = a.y; u.z = b.x; u.w = b.y;
  return __builtin_bit_cast(bf16x8, u);
}
// split 8 fp32 into hi/lo bf16x8 fragments
__device__ __forceinline__ void split8(const float* xv, bf16x8& hi, bf16x8& lo) {
  uint4v hv, lv;
#pragma unroll
  for (int jp = 0; jp < 4; ++jp) {
    float a0 = xv[2 * jp], a1 = xv[2 * jp + 1];
    u16 h0 = bbits(a0), h1 = bbits(a1);
    u16 l0 = bbits(a0 - bf2f(h0)), l1 = bbits(a1 - bf2f(h1));
    unsigned hh = (unsigned)h0 | ((unsigned)h1 << 16);
    unsigned ll = (unsigned)l0 | ((unsigned)l1 << 16);
    if (jp == 0) { hv.x = hh; lv.x = ll; }
    else if (jp == 1) { hv.y = hh; lv.y = ll; }
    else if (jp == 2) { hv.z = hh; lv.z = ll; }
    else { hv.w = hh; lv.w = ll; }
  }
  hi = __builtin_bit_cast(bf16x8, hv);
  lo = __builtin_bit_cast(bf16x8, lv);
}

// ===========================================================================
// SWIZZLED ("fragment-order") layouts — every MFMA fragment load is
// ldg16(base + (frag*64 + lane)*8): 64 lanes x 16B contiguous = coalesced.
//  K/Q planes (per b, 4096 pos x 64 ch):  [tile n32][kc 0..3][lane][j 0..7]
//     element: pos = tile*32 + (lane&31), ch = kc*16 + (lane>>5)*8 + j
//  V plane   (per b):                     [tile n32][kch 0..1][cbi 0..1][lane][j]
//     element: c = cbi*32 + (lane&31),   n = tile*32 + kch*16 + (lane>>5)*8 + j
//  weights theta/phi (64x128): [s*2+h][lane][j]: out = h*32+(lane&31),
//     in = s*16 + (lane>>5)*8 + j   (g: 64x64, s 0..3)
// ===========================================================================

__global__ __launch_bounds__(256) void pa_prep(
    const float* __restrict__ cw, const float* __restrict__ cbias,
    const float* __restrict__ gamma, const float* __restrict__ beta,
    const float* __restrict__ mean, const float* __restrict__ var,
    const float* __restrict__ tw, const float* __restrict__ pw, const float* __restrict__ gw,
    u16* __restrict__ Wt, float* __restrict__ bnA, float* __restrict__ bnB,
    u16* __restrict__ Wth, u16* __restrict__ Wtl,
    u16* __restrict__ Wph, u16* __restrict__ Wpl,
    u16* __restrict__ Wgh, u16* __restrict__ Wgl) {
  int i = blockIdx.x * 256 + threadIdx.x;
  if (i < 36864) {
    int ci = i & 63, co = (i >> 6) & 63, s = i >> 12;  // s = dy*3+dx
    Wt[(s * 64 + co) * 64 + ci] = bbits(cw[(co * 64 + ci) * 9 + s]);
  }
  if (i < 16384) {  // theta/phi swizzle, 8192 each
    int ii = i & 8191;
    int j = ii & 7, l = (ii >> 3) & 63, f = ii >> 9;  // f = s*2+h
    int out = (f & 1) * 32 + (l & 31);
    int in = (f >> 1) * 16 + (l >> 5) * 8 + j;
    const float* W = (i < 8192) ? tw : pw;
    float v = W[out * 128 + in];
    u16 h = bbits(v);
    u16 lo = bbits(v - bf2f(h));
    if (i < 8192) { Wth[ii] = h; Wtl[ii] = lo; }
    else { Wph[ii] = h; Wpl[ii] = lo; }
  } else if (i < 20480) {  // g swizzle, 4096
    int ii = i - 16384;
    int j = ii & 7, l = (ii >> 3) & 63, f = ii >> 9;  // f = s*2+h, s 0..3
    int out = (f & 1) * 32 + (l & 31);
    int in = (f >> 1) * 16 + (l >> 5) * 8 + j;
    float v = gw[out * 64 + in];
    u16 h = bbits(v);
    Wgh[ii] = h;
    Wgl[ii] = bbits(v - bf2f(h));
  }
  if (i < 64) {
    float rs = rsqrtf(var[i] + 1e-5f);
    float A = gamma[i] * rs;
    bnA[i] = A;
    bnB[i] = (cbias[i] - mean[i]) * A + beta[i];
  }
}

// ---------------------------------------------------------------------------
// Projections as MFMA GEMM, role-split: waves 0,1 theta->K | 2,3 phi->Q(hi/lo)
// | 4,5 g->V. Each wave owns one 32-position tile. Weights and outputs in
// fragment order (coalesced). Hi/lo split on W and X => fp32-grade results;
// K stored as plain bf16 (2-term QK split downstream).
// ---------------------------------------------------------------------------
template <bool LO>
__device__ __forceinline__ void store_qk_swz(const f32x16& a0, const f32x16& a1,
                                             const float* __restrict__ bias,
                                             u16* __restrict__ Hi, u16* __restrict__ Lo,
                                             int base, int l31, int q2) {
#pragma unroll
  for (int mt = 0; mt < 2; ++mt) {
    const f32x16& A = mt ? a1 : a0;
#pragma unroll
    for (int rq = 0; rq < 4; ++rq) {
      int ch = mt * 32 + rq * 8 + q2 * 4;
      float4 bb = *reinterpret_cast<const float4*>(bias + ch);
      float v0 = A[rq * 4 + 0] + bb.x;
      float v1 = A[rq * 4 + 1] + bb.y;
      float v2 = A[rq * 4 + 2] + bb.z;
      float v3 = A[rq * 4 + 3] + bb.w;
      int off = base + ((mt * 2 + (rq >> 1)) * 64 + l31 + 32 * (rq & 1)) * 8 + q2 * 4;
      u16 h0 = bbits(v0), h1 = bbits(v1), h2 = bbits(v2), h3 = bbits(v3);
      uint2v hv;
      hv.x = (unsigned)h0 | ((unsigned)h1 << 16);
      hv.y = (unsigned)h2 | ((unsigned)h3 << 16);
      *reinterpret_cast<uint2v*>(Hi + off) = hv;
      if (LO) {
        u16 l0 = bbits(v0 - bf2f(h0)), l1 = bbits(v1 - bf2f(h1));
        u16 l2 = bbits(v2 - bf2f(h2)), l3 = bbits(v3 - bf2f(h3));
        uint2v lv;
        lv.x = (unsigned)l0 | ((unsigned)l1 << 16);
        lv.y = (unsigned)l2 | ((unsigned)l3 << 16);
        *reinterpret_cast<uint2v*>(Lo + off) = lv;
      }
    }
  }
}

template <int NS>
__device__ __forceinline__ void gemm3(const u16* __restrict__ Wh, const u16* __restrict__ Wl,
                                      const bf16x8* Bh, const bf16x8* Bl,
                                      int lane, f32x16& a0, f32x16& a1) {
#pragma unroll
  for (int s = 0; s < NS; ++s) {
    bf16x8 w0h = ldg16(Wh + ((s * 2 + 0) * 64 + lane) * 8);
    bf16x8 w0l = ldg16(Wl + ((s * 2 + 0) * 64 + lane) * 8);
    bf16x8 w1h = ldg16(Wh + ((s * 2 + 1) * 64 + lane) * 8);
    bf16x8 w1l = ldg16(Wl + ((s * 2 + 1) * 64 + lane) * 8);
    a0 = MFMA32(w0h, Bh[s], a0);
    a0 = MFMA32(w0h, Bl[s], a0);
    a0 = MFMA32(w0l, Bh[s], a0);
    a1 = MFMA32(w1h, Bh[s], a1);
    a1 = MFMA32(w1h, Bl[s], a1);
    a1 = MFMA32(w1l, Bh[s], a1);
  }
}

__global__ __launch_bounds__(384, 2) void pa_proj(
    const float* __restrict__ H, const float* __restrict__ L,
    const float* __restrict__ tb, const float* __restrict__ pb, const float* __restrict__ gb,
    const u16* __restrict__ Wth, const u16* __restrict__ Wtl,
    const u16* __restrict__ Wph, const u16* __restrict__ Wpl,
    const u16* __restrict__ Wgh, const u16* __restrict__ Wgl,
    u16* __restrict__ Qh, u16* __restrict__ Ql,
    u16* __restrict__ Kh, u16* __restrict__ V) {
  int b = blockIdx.x >> 6;
  int tile64 = blockIdx.x & 63;
  int w = threadIdx.x >> 6;  // 0..5
  int lane = threadIdx.x & 63;
  int l31 = lane & 31, q2 = lane >> 5;
  int half = w & 1, role = w >> 1;  // 0 theta, 1 phi, 2 g
  int tile32 = tile64 * 2 + half;
  int n = tile32 * 32 + l31;
  int base = tile32 * 2048;  // u16 offset of this tile's fragment block (K/Q planes)

  if (role < 2) {
    bf16x8 Bh[8], Bl[8];
#pragma unroll
    for (int s = 0; s < 8; ++s) {
      const float* src = (s < 4) ? (H + (b * 64 + s * 16) * 4096)
                                 : (L + (b * 64 + (s - 4) * 16) * 4096);
      const float* pp = src + (q2 * 8) * 4096 + n;
      float xv[8];
#pragma unroll
      for (int j = 0; j < 8; ++j) xv[j] = pp[j * 4096];
      split8(xv, Bh[s], Bl[s]);
    }
    f32x16 a0 = {}, a1 = {};
    if (role == 0) {
      gemm3<8>(Wth, Wtl, Bh, Bl, lane, a0, a1);
      store_qk_swz<false>(a0, a1, tb, Kh + b * 262144, (u16*)nullptr, base, l31, q2);
    } else {
      gemm3<8>(Wph, Wpl, Bh, Bl, lane, a0, a1);
      store_qk_swz<true>(a0, a1, pb, Qh + b * 262144, Ql + b * 262144, base, l31, q2);
    }
  } else {
    bf16x8 Bh[4], Bl[4];
#pragma unroll
    for (int s = 0; s < 4; ++s) {
      const float* pp = L + (b * 64 + s * 16 + q2 * 8) * 4096 + n;
      float xv[8];
#pragma unroll
      for (int j = 0; j < 8; ++j) xv[j] = pp[j * 4096];
      split8(xv, Bh[s], Bl[s]);
    }
    f32x16 a0 = {}, a1 = {};
    gemm3<4>(Wgh, Wgl, Bh, Bl, lane, a0, a1);
    // V store in fragment order: addr=(((tile*2+kch)*2+cbi)*64 + lane_v)*8 + jn
    u16* Vb = V + b * 262144;
    int kch = (l31 >> 4) & 1, q2v = (l31 >> 3) & 1, jn = l31 & 7;
#pragma unroll
    for (int mt = 0; mt < 2; ++mt) {
      const f32x16& A = mt ? a1 : a0;
#pragma unroll
      for (int rq = 0; rq < 4; ++rq) {
        int ch = mt * 32 + rq * 8 + q2 * 4;
        float4 bb = *reinterpret_cast<const float4*>(gb + ch);
        float vv[4] = {A[rq * 4 + 0] + bb.x, A[rq * 4 + 1] + bb.y,
                       A[rq * 4 + 2] + bb.z, A[rq * 4 + 3] + bb.w};
#pragma unroll
        for (int i2 = 0; i2 < 4; ++i2) {
          int c31 = rq * 8 + q2 * 4 + i2;
          int lane_v = c31 + 32 * q2v;
          Vb[(((tile32 * 2 + kch) * 2 + mt) * 64 + lane_v) * 8 + jn] = bbits(vv[i2]);
        }
      }
    }
  }
}

// ---------------------------------------------------------------------------
// Flash attention v3: O^T[c,m] = sum_n softmax_n(K[n,:]·Q[m,:]) * V[c,n]
// Grid 512 = (b, m-tile 32). 512 thr = 8 waves (n split 8-way, 16 iters x 32
// keys), 2 blocks/CU -> 4 waves/SIMD. Q (hi/lo) in registers (fragment-order
// loads, coalesced). 2-term QK split: kh(qh+ql). Fixed-M softmax (frozen
// after wave's first tile; exact merge at end). Only LDS use: per-wave P
// round trip + final merge overlay. VGPR budget ~124 (cap 128 via
// __launch_bounds__(512,4)).
// C/D layout: col=lane&31, row=(r&3)+8*(r>>2)+4*(lane>>5).
// ---------------------------------------------------------------------------
__global__ __launch_bounds__(512, 4) void pa_flash(
    const u16* __restrict__ Qhg, const u16* __restrict__ Qlg,
    const u16* __restrict__ Khg, const u16* __restrict__ Vg, u16* __restrict__ E) {
  __shared__ __align__(16) char smem[18432];
  u16* Pb = (u16*)smem;  // [8 waves][32 m][36] u16
  // post-loop overlay:
  float* Obuf = (float*)smem;             // [64 c][33 m] f32 = 8448 B
  float* MLm = (float*)(smem + 8448);     // [8][32]
  float* MLl = (float*)(smem + 9472);     // [8][32]
  float* Lst = (float*)(smem + 10496);    // [32]

  int tid = threadIdx.x;
  int w = tid >> 6, lane = tid & 63;
  int l31 = lane & 31, q2 = lane >> 5;
  int b = blockIdx.x >> 7, mt = blockIdx.x & 127;
  int m0 = mt * 32;
  int bq = b * 4096;
  const u16* Qb = Qhg + b * 262144;
  const u16* Qlb = Qlg + b * 262144;
  const u16* Kb = Khg + b * 262144;
  const u16* Vb = Vg + b * 262144;

  // Q fragments in registers (coalesced fragment-order loads)
  bf16x8 qh[4], ql[4];
#pragma unroll
  for (int kc = 0; kc < 4; ++kc) {
    qh[kc] = ldg16(Qb + ((mt * 4 + kc) * 64 + lane) * 8);
    ql[kc] = ldg16(Qlb + ((mt * 4 + kc) * 64 + lane) * 8);
  }

  f32x16 accO[2] = {};  // [cbi], C layout: row=c, col=m
  float Mm = 0.f, Ll = 0.f;
  u16* mypb = Pb + w * (32 * 36);
  u16* prow = mypb + l31 * 36;

#pragma unroll 1
  for (int it = 0; it < 16; ++it) {
    int tile = it * 8 + w;  // this wave's 32-key tile index

    bf16x8 kh[4];
#pragma unroll
    for (int kc = 0; kc < 4; ++kc) kh[kc] = ldg16(Kb + ((tile * 4 + kc) * 64 + lane) * 8);
    bf16x8 vf[2][2];
#pragma unroll
    for (int kch = 0; kch < 2; ++kch)
#pragma unroll
      for (int cbi = 0; cbi < 2; ++cbi)
        vf[cbi][kch] = ldg16(Vb + (((tile * 2 + kch) * 2 + cbi) * 64 + lane) * 8);

    // QK: S^T = K·(Qh+Ql)^T, single 8-deep chain
    f32x16 a = {};
#pragma unroll
    for (int kc = 0; kc < 4; ++kc) {
      a = MFMA32(kh[kc], qh[kc], a);
      a = MFMA32(kh[kc], ql[kc], a);
    }
    if (it == 0) {  // freeze M from the wave's first tile (wave-uniform branch)
      float tmax = a[0];
#pragma unroll
      for (int r = 1; r < 16; ++r) tmax = fmaxf(tmax, a[r]);
      tmax = fmaxf(tmax, __shfl_xor(tmax, 32, 64));
      Mm = tmax;
    }
    float pv[16];
    float psum = 0.f;
#pragma unroll
    for (int r = 0; r < 16; ++r) {
      pv[r] = __expf(a[r] - Mm);
      psum += pv[r];
    }
    psum += __shfl_xor(psum, 32, 64);
    Ll += psum;
    // P: C-layout regs -> LDS [m][n]; reg quad rq holds n = 8*rq+4*q2+0..3
#pragma unroll
    for (int rq = 0; rq < 4; ++rq) {
      unsigned lo = (unsigned)bbits(pv[rq * 4 + 0]) | ((unsigned)bbits(pv[rq * 4 + 1]) << 16);
      unsigned hi = (unsigned)bbits(pv[rq * 4 + 2]) | ((unsigned)bbits(pv[rq * 4 + 3]) << 16);
      uint2v uu;
      uu.x = lo;
      uu.y = hi;
      *reinterpret_cast<uint2v*>(prow + rq * 8 + q2 * 4) = uu;
    }
    // PV: O^T += V^T(A) · P^T(B)
    bf16x8 p0 = ld_p8(prow + q2 * 8);       // k = n 0..15
    bf16x8 p1 = ld_p8(prow + 16 + q2 * 8);  // k = n 16..31
    accO[0] = MFMA32(vf[0][0], p0, accO[0]);
    accO[0] = MFMA32(vf[0][1], p1, accO[0]);
    accO[1] = MFMA32(vf[1][0], p0, accO[1]);
    accO[1] = MFMA32(vf[1][1], p1, accO[1]);
  }

  // ---- exact merge of 8 waves' (O, M, l); merge buffers overlay Pbuf ----
  __syncthreads();
  if (q2 == 0) {
    MLm[w * 32 + l31] = Mm;
    MLl[w * 32 + l31] = Ll;
  }
  __syncthreads();
  float M = MLm[l31];
  for (int ww = 1; ww < 8; ++ww) M = fmaxf(M, MLm[ww * 32 + l31]);
  float ls = 0.f;
  for (int ww = 0; ww < 8; ++ww) ls += MLl[ww * 32 + l31] * __expf(MLm[ww * 32 + l31] - M);
  float mysc = __expf(Mm - M);
  if (w == 0 && q2 == 0) Lst[l31] = ls;
  for (int ww = 0; ww < 8; ++ww) {
    if (w == ww) {
#pragma unroll
      for (int cbi = 0; cbi < 2; ++cbi)
#pragma unroll
        for (int r = 0; r < 16; ++r) {
          int c = cbi * 32 + (r & 3) + 8 * (r >> 2) + 4 * q2;
          float* dst = &Obuf[c * 33 + l31];
          float v = accO[cbi][r] * mysc;
          if (ww == 0)
            *dst = v;
          else
            *dst += v;
        }
    }
    __syncthreads();
  }
  // write E[b][m][c] bf16 (spatial-major for the conv's B-operand)
  int em = tid >> 4, ec0 = (tid & 15) * 4;
  float invl = 1.0f / Lst[em];
  float v0 = Obuf[(ec0 + 0) * 33 + em] * invl;
  float v1 = Obuf[(ec0 + 1) * 33 + em] * invl;
  float v2 = Obuf[(ec0 + 2) * 33 + em] * invl;
  float v3 = Obuf[(ec0 + 3) * 33 + em] * invl;
  uint2v u0;
  u0.x = (unsigned)bbits(v0) | ((unsigned)bbits(v1) << 16);
  u0.y = (unsigned)bbits(v2) | ((unsigned)bbits(v3) << 16);
  *reinterpret_cast<uint2v*>(E + (bq + m0 + em) * 64 + ec0) = u0;
}

// ---------------------------------------------------------------------------
// Conv3x3(SAME)+BN+ReLU+residual as 9 shifted MFMA GEMMs.
// Block = (b, row y). LDS holds rows y-1..y+1 with x-halo, [x+1][c] stride 68.
// ---------------------------------------------------------------------------
__global__ __launch_bounds__(256) void pa_conv(
    const u16* __restrict__ E, const u16* __restrict__ Wt,
    const float* __restrict__ bnA, const float* __restrict__ bnB,
    const float* __restrict__ H, float* __restrict__ out) {
  __shared__ u16 Er[3][66 * 68];
  int tid = threadIdx.x;
  int blk = blockIdx.x;
  int b = blk >> 6, y = blk & 63;
  int lane = tid & 63;
  int l31 = lane & 31, q2 = lane >> 5;
  int wv = tid >> 6;
  int cbi = wv >> 1, mb = wv & 1;
  int s0 = (y == 0) ? 1 : 0;
  int s1 = (y == 63) ? 1 : 2;

  for (int s = s0; s <= s1; ++s) {
    int yy = y + s - 1;
#pragma unroll
    for (int rep = 0; rep < 2; ++rep) {
      int id = rep * 256 + tid;
      int x = id >> 3, co = (id & 7) * 8;
      const uint2v* src = reinterpret_cast<const uint2v*>(E + ((b * 4096 + yy * 64 + x) * 64 + co));
      uint2v a = src[0], b4 = src[1];
      u16* d = &Er[s][(x + 1) * 68 + co];
      *reinterpret_cast<uint2v*>(d) = a;
      *reinterpret_cast<uint2v*>(d + 4) = b4;
    }
  }
  if (tid < 96) {  // zero x-halo columns
    int s = tid >> 5, side = (tid >> 4) & 1, co = (tid & 15) * 4;
    uint2v z;
    z.x = 0;
    z.y = 0;
    *reinterpret_cast<uint2v*>(&Er[s][(side ? 65 : 0) * 68 + co]) = z;
  }
  __syncthreads();

  f32x16 acc = {};
  for (int s = s0; s <= s1; ++s) {
#pragma unroll
    for (int dx = 0; dx < 3; ++dx)
#pragma unroll
      for (int kc = 0; kc < 4; ++kc) {
        bf16x8 a = ldg16(Wt + ((s * 3 + dx) * 64 + cbi * 32 + l31) * 64 + kc * 16 + q2 * 8);
        const u16* pbr = &Er[s][(mb * 32 + l31 + dx) * 68 + kc * 16 + q2 * 8];
        bf16x8 bb = ld_p8(pbr);
        acc = MFMA32(a, bb, acc);
      }
  }
#pragma unroll
  for (int r = 0; r < 16; ++r) {
    int c = cbi * 32 + (r & 3) + 8 * (r >> 2) + 4 * q2;
    int x = mb * 32 + l31;
    float v = acc[r] * bnA[c] + bnB[c];
    v = fmaxf(v, 0.f);
    int idx = ((b * 64 + c) * 64 + y) * 64 + x;
    out[idx] = H[idx] + v;
  }
}

// ---------------------------------------------------------------------------
extern "C" void kernel_launch(void* const* d_in, const int* in_sizes, int n_in,
                              void* d_out, int out_size, void* d_ws, size_t ws_size,
                              hipStream_t stream) {
  (void)in_sizes; (void)n_in; (void)out_size; (void)ws_size;
  const float* H = (const float*)d_in[0];
  const float* L = (const float*)d_in[1];
  const float* tw = (const float*)d_in[2];
  const float* tb = (const float*)d_in[3];
  const float* pw = (const float*)d_in[4];
  const float* pb = (const float*)d_in[5];
  const float* gw = (const float*)d_in[6];
  const float* gb = (const float*)d_in[7];
  const float* cw = (const float*)d_in[8];
  const float* cb = (const float*)d_in[9];
  const float* gamma = (const float*)d_in[10];
  const float* beta = (const float*)d_in[11];
  const float* mean = (const float*)d_in[12];
  const float* var = (const float*)d_in[13];

  const int NC = 16384 * 64;  // 1M u16 per plane (4 b x 262144)
  u16* Qh = (u16*)d_ws;
  u16* Ql = Qh + NC;
  u16* Kh = Ql + NC;
  u16* Vv = Kh + NC;
  u16* Eb = Vv + NC;
  u16* Wt = Eb + NC;                  // 36864 u16
  float* bnA = (float*)(Wt + 36864);  // 64 f32
  float* bnB = bnA + 64;              // 64 f32
  u16* Wth = (u16*)(bnB + 64);
  u16* Wtl = Wth + 8192;
  u16* Wph = Wtl + 8192;
  u16* Wpl = Wph + 8192;
  u16* Wgh = Wpl + 8192;  // 4096
  u16* Wgl = Wgh + 4096;  // 4096

  pa_prep<<<144, 256, 0, stream>>>(cw, cb, gamma, beta, mean, var, tw, pw, gw,
                                   Wt, bnA, bnB, Wth, Wtl, Wph, Wpl, Wgh, Wgl);
  pa_proj<<<256, 384, 0, stream>>>(H, L, tb, pb, gb, Wth, Wtl, Wph, Wpl, Wgh, Wgl,
                                   Qh, Ql, Kh, Vv);
  pa_flash<<<512, 512, 0, stream>>>(Qh, Ql, Kh, Vv, Eb);
  pa_conv<<<256, 256, 0, stream>>>(Eb, Wt, bnA, bnB, H, (float*)d_out);
}